// Round 4
// baseline (168.379 us; speedup 1.0000x reference)
//
#include <hip/hip_runtime.h>
#include <stdint.h>

typedef __attribute__((ext_vector_type(4))) int int4v;          // MFMA i8 A/B (16 i8) and i32 C/D
typedef __attribute__((ext_vector_type(16))) unsigned char uchar16;

#define MDIM 8192
#define KDIM 2048
#define NDIM 2048
#define BM 128
#define BN 128
#define BK 128   // i8 k per tile; rows are 128 B = 8 x 16B chunks

// async global->LDS, 16B per lane. LDS dest = wave-uniform base + lane*16.
__device__ __forceinline__ void load16_lds(const void* g, void* l) {
  __builtin_amdgcn_global_load_lds(
      (const __attribute__((address_space(1))) void*)g,
      (__attribute__((address_space(3))) void*)l, 16, 0, 0);
}

// ---- Phase 1 (fused): binarize X -> i8 [M][K]; binarize+transpose W -> i8 [N][K] ----
#define XBLK 4096   // M*K / (256*16)
#define WBLK 1024   // N*K / (256*16)

__global__ void binarize_fused(const float* __restrict__ X,
                               const float* __restrict__ W,
                               unsigned char* __restrict__ Xb,
                               unsigned char* __restrict__ WbT) {
  const int b = blockIdx.x;
  if (b < XBLK) {
    size_t i = ((size_t)b * 256 + threadIdx.x) * 16;
    const float4* xp = (const float4*)(X + i);
    uchar16 o;
#pragma unroll
    for (int h = 0; h < 4; ++h) {
      float4 a = xp[h];
      o[4 * h + 0] = (a.x < 0.f) ? 0xFFu : 0x01u;
      o[4 * h + 1] = (a.y < 0.f) ? 0xFFu : 0x01u;
      o[4 * h + 2] = (a.z < 0.f) ? 0xFFu : 0x01u;
      o[4 * h + 3] = (a.w < 0.f) ? 0xFFu : 0x01u;
    }
    *(uchar16*)(Xb + i) = o;
  } else {
    const int bw = b - XBLK;
    const int nb = bw & 31;                       // n-block (64 wide)
    const int kb = bw >> 5;                       // 64-k block
    const int nn = threadIdx.x & 63;              // lane -> consecutive n (coalesced reads)
    const int kc = kb * 4 + (threadIdx.x >> 6);   // 16-k chunk id, 0..127
    const float* wp = W + (size_t)(kc * 16) * NDIM + nb * 64 + nn;
    uchar16 o;
#pragma unroll
    for (int j = 0; j < 16; ++j)
      o[j] = (wp[(size_t)j * NDIM] < 0.f) ? 0xFFu : 0x01u;
    *(uchar16*)(WbT + (size_t)(nb * 64 + nn) * KDIM + kc * 16) = o;
  }
}

// ---- Phase 2: i8 MFMA GEMM, XOR-swizzled LDS, n-fast grid for W L2-residency ----
// C[M][N] = A[M][K] * B[N][K]^T + bias, exact integer accumulation in i32.
// Grid: x = n-block (16 wide, fast) -> 16 consecutive blocks share one A panel
// (L2-hit) and cover all of W (4 MB = one XCD L2, stays resident).
__global__ __launch_bounds__(256) void gemm_bin_i8(
    const unsigned char* __restrict__ A,    // Xb  [M][K] i8 (+1/-1)
    const unsigned char* __restrict__ B,    // WbT [N][K] i8 (+1/-1)
    const float* __restrict__ bias,         // [N]
    float* __restrict__ C) {                // [M][N] fp32
  __shared__ __align__(16) unsigned char As[BM * BK];  // 16 KB
  __shared__ __align__(16) unsigned char Bs[BN * BK];  // 16 KB

  const int tid = threadIdx.x;
  const int lane = tid & 63;
  const int wv = tid >> 6;     // wave 0..3
  const int wm = wv >> 1;      // wave row (64 rows)
  const int wn = wv & 1;       // wave col (64 cols)
  const int r = lane & 15;     // MFMA m/n index
  const int q = lane >> 4;     // MFMA quad

  const int n0 = blockIdx.x * BN;   // fast axis: n
  const int m0 = blockIdx.y * BM;   // slow axis: m

  int4v acc[4][4] = {};

  const int qbase = wv * 256;  // this wave's 16B-chunk slot base (1024 chunks/tile)

  // per-lane staging source offsets (slot -> XOR-swizzled global chunk, same row)
  int srcoff[4];
#pragma unroll
  for (int i = 0; i < 4; ++i) {
    const int s = qbase + i * 64 + lane;
    const int row = s >> 3;
    const int cg = (s & 7) ^ (row & 7);   // global 16B chunk for this LDS slot
    srcoff[i] = row * KDIM + cg * 16;     // bytes
  }

  for (int kb = 0; kb < KDIM; kb += BK) {
#pragma unroll
    for (int i = 0; i < 4; ++i) {
      load16_lds(A + (size_t)m0 * KDIM + kb + srcoff[i],
                 As + (size_t)(qbase + i * 64) * 16);
      load16_lds(B + (size_t)n0 * KDIM + kb + srcoff[i],
                 Bs + (size_t)(qbase + i * 64) * 16);
    }
    __syncthreads();  // drains vmcnt (global_load_lds) before reads

#pragma unroll
    for (int s2 = 0; s2 < 2; ++s2) {  // two k=64 substeps of BK=128
      const int cswz = ((s2 * 4 + q) ^ (r & 7)) * 16;  // swizzled chunk byte offset
      int4v af[4], bf[4];
#pragma unroll
      for (int t = 0; t < 4; ++t) {
        // A frag: A[m = lane&15][k = q*16 + j], j=0..15 (16 contiguous i8)
        af[t] = *(const int4v*)(As + (wm * 64 + t * 16 + r) * BK + cswz);
        bf[t] = *(const int4v*)(Bs + (wn * 64 + t * 16 + r) * BK + cswz);
      }
#pragma unroll
      for (int tm = 0; tm < 4; ++tm)
#pragma unroll
        for (int tn = 0; tn < 4; ++tn)
          acc[tm][tn] = __builtin_amdgcn_mfma_i32_16x16x64_i8(
              af[tm], bf[tn], acc[tm][tn], 0, 0, 0);
    }
    __syncthreads();
  }

  // epilogue: C/D layout col=lane&15, row=q*4+v (dtype-independent, m121-128)
#pragma unroll
  for (int tn = 0; tn < 4; ++tn) {
    const int col = n0 + wn * 64 + tn * 16 + r;
    const float bv = bias[col];
#pragma unroll
    for (int tm = 0; tm < 4; ++tm) {
      const int rowb = m0 + wm * 64 + tm * 16 + q * 4;
#pragma unroll
      for (int v = 0; v < 4; ++v)
        C[(size_t)(rowb + v) * NDIM + col] = (float)acc[tm][tn][v] + bv;
    }
  }
}

extern "C" void kernel_launch(void* const* d_in, const int* in_sizes, int n_in,
                              void* d_out, int out_size, void* d_ws, size_t ws_size,
                              hipStream_t stream) {
  const float* X = (const float*)d_in[0];     // [8192, 2048]
  const float* W = (const float*)d_in[1];     // [2048, 2048]
  const float* bias = (const float*)d_in[2];  // [2048]
  float* out = (float*)d_out;

  unsigned char* Xb = (unsigned char*)d_ws;                 // 16 MB
  unsigned char* WbT = Xb + (size_t)MDIM * KDIM;            // 4 MB (ws 20 MB)

  binarize_fused<<<dim3(XBLK + WBLK), 256, 0, stream>>>(X, W, Xb, WbT);
  gemm_bin_i8<<<dim3(NDIM / BN, MDIM / BM), 256, 0, stream>>>(Xb, WbT, bias, out);
}

// Round 5
// 144.748 us; speedup vs baseline: 1.1633x; 1.1633x over previous
//
#include <hip/hip_runtime.h>
#include <stdint.h>

typedef __attribute__((ext_vector_type(4))) int int4v;           // 16B LDS frag (fp4 x32)
typedef __attribute__((ext_vector_type(8))) int int8v;           // MFMA f8f6f4 A/B operand
typedef __attribute__((ext_vector_type(4))) float floatx4;       // MFMA C/D
typedef __attribute__((ext_vector_type(16))) unsigned char uchar16;

#define MDIM 8192
#define KDIM 2048
#define NDIM 2048
#define BM 128
#define BN 128
#define KB 1024      // bytes per packed fp4 row (K/2)
#define BKB 128      // staged bytes per row per tile = 256 fp4 k-elements

// async global->LDS, 16B per lane. LDS dest = wave-uniform base + lane*16.
__device__ __forceinline__ void load16_lds(const void* g, void* l) {
  __builtin_amdgcn_global_load_lds(
      (const __attribute__((address_space(1))) void*)g,
      (__attribute__((address_space(3))) void*)l, 16, 0, 0);
}

// ---- Phase 1 (fused): binarize X -> fp4 [M][K/2]; binarize+transpose W -> fp4 [N][K/2] ----
// fp4 e2m1: +1 = 0x2, -1 = 0xA. Low nibble = even k (A and B packed identically,
// so any within-k permutation cancels in the dot product).
#define XBLK 2048   // M*K / (256*32)
#define WBLK 512    // N*K / (256*32)

__global__ void binarize_fused(const float* __restrict__ X,
                               const float* __restrict__ W,
                               unsigned char* __restrict__ Xb,
                               unsigned char* __restrict__ WbT) {
  const int b = blockIdx.x;
  if (b < XBLK) {
    size_t i = ((size_t)b * 256 + threadIdx.x) * 32;   // element index, 32/thread
    const float4* xp = (const float4*)(X + i);
    uchar16 o;
#pragma unroll
    for (int h = 0; h < 8; ++h) {
      float4 a = xp[h];
      unsigned n0 = (a.x < 0.f) ? 0xAu : 0x2u;
      unsigned n1 = (a.y < 0.f) ? 0xAu : 0x2u;
      unsigned n2 = (a.z < 0.f) ? 0xAu : 0x2u;
      unsigned n3 = (a.w < 0.f) ? 0xAu : 0x2u;
      o[2 * h]     = (unsigned char)(n0 | (n1 << 4));
      o[2 * h + 1] = (unsigned char)(n2 | (n3 << 4));
    }
    *(uchar16*)(Xb + i / 2) = o;
  } else {
    const int bw = b - XBLK;
    const int nb = bw & 31;                       // n-block (64 wide)
    const int kb = bw >> 5;                       // 0..15
    const int nn = threadIdx.x & 63;              // lane -> consecutive n (coalesced reads)
    const int kc = kb * 4 + (threadIdx.x >> 6);   // 32-k chunk id, 0..63
    const float* wp = W + (size_t)(kc * 32) * NDIM + nb * 64 + nn;
    uchar16 o;
#pragma unroll
    for (int j = 0; j < 16; ++j) {
      unsigned lo = (wp[(size_t)(2 * j) * NDIM] < 0.f) ? 0xAu : 0x2u;
      unsigned hi = (wp[(size_t)(2 * j + 1) * NDIM] < 0.f) ? 0xAu : 0x2u;
      o[j] = (unsigned char)(lo | (hi << 4));
    }
    *(uchar16*)(WbT + (size_t)(nb * 64 + nn) * KB + kc * 16) = o;
  }
}

// ---- Phase 2: MX-fp4 MFMA GEMM, XOR-swizzled LDS (byte-identical to the R3
// structure that measured ZERO bank conflicts). C = A * B^T + bias, exact:
// fp4 {+1,-1} inputs, fp32 accumulation of integers <= 2048.
__global__ __launch_bounds__(256) void gemm_bin_fp4(
    const unsigned char* __restrict__ A,    // Xb  [M][K/2] fp4
    const unsigned char* __restrict__ B,    // WbT [N][K/2] fp4
    const float* __restrict__ bias,         // [N]
    float* __restrict__ C) {                // [M][N] fp32
  __shared__ __align__(16) unsigned char As[BM * BKB];  // 16 KB
  __shared__ __align__(16) unsigned char Bs[BN * BKB];  // 16 KB

  const int tid = threadIdx.x;
  const int lane = tid & 63;
  const int wv = tid >> 6;     // wave 0..3
  const int wm = wv >> 1;      // wave row (64 rows)
  const int wn = wv & 1;       // wave col (64 cols)
  const int r = lane & 15;     // MFMA m/n index
  const int q = lane >> 4;     // MFMA quad (k-block select)

  const int m0 = blockIdx.x * BM;   // m-fast grid (R3 layout; R4 showed n-fast is worse)
  const int n0 = blockIdx.y * BN;

  floatx4 acc[4][4] = {};

  const int qbase = wv * 256;  // this wave's 16B-chunk slot base (1024 chunks/tile)

  // per-lane staging source offsets (slot -> XOR-swizzled global chunk, same row)
  int srcoff[4];
#pragma unroll
  for (int i = 0; i < 4; ++i) {
    const int s = qbase + i * 64 + lane;
    const int row = s >> 3;
    const int cg = (s & 7) ^ (row & 7);   // global 16B chunk for this LDS slot
    srcoff[i] = row * KB + cg * 16;       // bytes
  }

  for (int kb = 0; kb < KB; kb += BKB) {  // 8 K-tiles of 256 fp4 elements
#pragma unroll
    for (int i = 0; i < 4; ++i) {
      load16_lds(A + (size_t)m0 * KB + kb + srcoff[i],
                 As + (size_t)(qbase + i * 64) * 16);
      load16_lds(B + (size_t)n0 * KB + kb + srcoff[i],
                 Bs + (size_t)(qbase + i * 64) * 16);
    }
    __syncthreads();  // drains vmcnt (global_load_lds) before reads

#pragma unroll
    for (int s2 = 0; s2 < 2; ++s2) {  // two k=128 substeps of the 256-k tile
      const int cswz = ((s2 * 4 + q) ^ (r & 7)) * 16;  // swizzled chunk byte offset
      int8v a8[4], b8[4];
#pragma unroll
      for (int t = 0; t < 4; ++t) {
        // lane's frag: row = lane&15, k-block = q (32 fp4 = 16 B); fp4 uses regs [0:3]
        int4v av = *(const int4v*)(As + (wm * 64 + t * 16 + r) * BKB + cswz);
        int4v bv = *(const int4v*)(Bs + (wn * 64 + t * 16 + r) * BKB + cswz);
        a8[t] = int8v{av[0], av[1], av[2], av[3], 0, 0, 0, 0};
        b8[t] = int8v{bv[0], bv[1], bv[2], bv[3], 0, 0, 0, 0};
      }
#pragma unroll
      for (int tm = 0; tm < 4; ++tm)
#pragma unroll
        for (int tn = 0; tn < 4; ++tn)
          // cbsz=4 (A fmt fp4 e2m1), blgp=4 (B fmt fp4); scales = E8M0 127 -> 1.0
          acc[tm][tn] = __builtin_amdgcn_mfma_scale_f32_16x16x128_f8f6f4(
              a8[tm], b8[tn], acc[tm][tn], 4, 4,
              0, 0x7F7F7F7F, 0, 0x7F7F7F7F);
    }
    __syncthreads();
  }

  // epilogue: C/D layout col=lane&15, row=q*4+v (shape-determined, m121-128)
#pragma unroll
  for (int tn = 0; tn < 4; ++tn) {
    const int col = n0 + wn * 64 + tn * 16 + r;
    const float bv = bias[col];
#pragma unroll
    for (int tm = 0; tm < 4; ++tm) {
      const int rowb = m0 + wm * 64 + tm * 16 + q * 4;
#pragma unroll
      for (int v = 0; v < 4; ++v)
        C[(size_t)(rowb + v) * NDIM + col] = acc[tm][tn][v] + bv;
    }
  }
}

extern "C" void kernel_launch(void* const* d_in, const int* in_sizes, int n_in,
                              void* d_out, int out_size, void* d_ws, size_t ws_size,
                              hipStream_t stream) {
  const float* X = (const float*)d_in[0];     // [8192, 2048]
  const float* W = (const float*)d_in[1];     // [2048, 2048]
  const float* bias = (const float*)d_in[2];  // [2048]
  float* out = (float*)d_out;

  unsigned char* Xb = (unsigned char*)d_ws;                 // 8 MB (fp4 packed)
  unsigned char* WbT = Xb + (size_t)MDIM * KDIM / 2;        // 2 MB (ws 10 MB)

  binarize_fused<<<dim3(XBLK + WBLK), 256, 0, stream>>>(X, W, Xb, WbT);
  gemm_bin_fp4<<<dim3(MDIM / BM, NDIM / BN), 256, 0, stream>>>(Xb, WbT, bias, out);
}